// Round 1
// baseline (2294.760 us; speedup 1.0000x reference)
//
#include <hip/hip_runtime.h>
#include <math.h>

#define H 512
#define W 512
#define TBINS 180
#define RBINS 360
#define NPIX (H*W)

// Derived constants (match reference fp32 edge construction)
#define THETA_MIN (-1.5707963267948966f)
#define T_BIN ((float)(3.141592653589793 / 179.0))
#define RHO_MAX (724.0773439350246f)
#define R_MIN (-724.0773439350246f)
#define R_BIN ((float)(2.0 * 724.0773439350246 / 359.0))
#define THR_VAR 100.0f

// Gaussian CDF (matches scipy/jax ndtr = 0.5*erfc(-z/sqrt(2)))
__device__ __forceinline__ float phi_cdf(float z) {
    return 0.5f * erfcf(-0.70710678118654752f * z);
}

struct PixParams {
    float theta, rho, var_theta, var_rho;
};

// Per-pixel plane fit + uncertainty propagation (faithful to reference,
// including the row_s quirk: residual uses img[clip(hi+dx), wi] only).
__device__ __forceinline__ PixParams compute_pixel(const float* __restrict__ img,
                                                   int hi, int wi) {
    int xm = max(hi - 1, 0), xp = min(hi + 1, H - 1);
    int ym = max(wi - 1, 0), yp = min(wi + 1, W - 1);

    const float* r0 = img + xm * W;   // dx = -1
    const float* r1 = img + hi * W;   // dx =  0
    const float* r2 = img + xp * W;   // dx = +1

    float s00 = r0[ym], s01 = r0[wi], s02 = r0[yp];
    float s10 = r1[ym], s11 = r1[wi], s12 = r1[yp];
    float s20 = r2[ym], s21 = r2[wi], s22 = r2[yp];

    // alpha: sum dx*s ; beta: sum dy*s ; gamma: mean
    float alpha_s = (s20 + s21 + s22) - (s00 + s01 + s02);
    float beta_s  = (s02 + s12 + s22) - (s00 + s10 + s20);
    float gsum    = s00 + s01 + s02 + s10 + s11 + s12 + s20 + s21 + s22;

    float alpha = alpha_s * (1.0f / 6.0f) + 1e-6f;
    float beta  = beta_s  * (1.0f / 6.0f) + 1e-6f;
    float gamma = gsum * (1.0f / 9.0f);

    // residual: r = img[clip(hi+dx), wi] - alpha*dy - beta*dx - gamma
    float cvals[3] = { s01, s11, s21 };   // center column, dx = -1,0,+1
    float eps2 = 0.0f;
    #pragma unroll
    for (int ix = 0; ix < 3; ++ix) {
        float dx = (float)(ix - 1);
        float c = cvals[ix];
        #pragma unroll
        for (int iy = 0; iy < 3; ++iy) {
            float dy = (float)(iy - 1);
            float r = c - alpha * dy - beta * dx - gamma;
            eps2 += r * r;
        }
    }
    float noise_var = eps2 * (1.0f / 7.0f);      // n_win - 2
    float va = noise_var * (1.0f / 6.0f);        // var_alpha = var_beta
    float g2 = alpha * alpha + beta * beta;
    float var_theta = (beta * beta * va + alpha * alpha * va) / (g2 * g2);

    float theta = atanf(beta / alpha);
    float ct = cosf(theta), st = sinf(theta);
    float x = (float)hi, y = (float)wi;
    float rho = x * ct + y * st;
    float drho = -x * st + y * ct;
    float var_rho = drho * drho * var_theta;

    PixParams pp;
    pp.theta = theta; pp.rho = rho; pp.var_theta = var_theta; pp.var_rho = var_rho;
    return pp;
}

__global__ void init_kernel(float* __restrict__ acc, int* __restrict__ count) {
    int i = blockIdx.x * blockDim.x + threadIdx.x;
    if (i < TBINS * RBINS) acc[i] = 0.0f;
    if (i == 0) *count = 0;
}

__global__ void prep_kernel(const float* __restrict__ img,
                            const float* __restrict__ mask,
                            int* __restrict__ count,
                            int* __restrict__ list) {
    int p = blockIdx.x * blockDim.x + threadIdx.x;
    if (p >= NPIX) return;
    int hi = p >> 9;
    int wi = p & (W - 1);
    PixParams pp = compute_pixel(img, hi, wi);
    bool valid = (pp.var_theta <= THR_VAR) && (pp.var_rho <= THR_VAR) && (mask[p] != 0.0f);
    if (valid) {
        int pos = atomicAdd(count, 1);
        list[pos] = p;
    }
}

// One wave (64 lanes) per valid pixel. Lane t owns theta bins t, t+64, t+128.
// Rho support is windowed (sigma_r <= 10 due to validity gate => <= ~46 bins).
__global__ void vote_kernel(const float* __restrict__ img,
                            const float* __restrict__ mask,
                            const int* __restrict__ list,
                            const int* __restrict__ count,
                            float* __restrict__ acc) {
    int n = *count;
    int gid = blockIdx.x * blockDim.x + threadIdx.x;
    int wave = gid >> 6;
    int lane = threadIdx.x & 63;
    int nwaves = (gridDim.x * blockDim.x) >> 6;

    for (int i = wave; i < n; i += nwaves) {
        int p = list[i];
        int hi = p >> 9;
        int wi = p & (W - 1);

        // recompute params (wave-uniform; image is L2-resident, cheap)
        PixParams pp = compute_pixel(img, hi, wi);
        float sig_t = sqrtf(pp.var_theta + 1e-12f);
        float sig_r = sqrtf(pp.var_rho + 1e-12f);
        float inv_st = 1.0f / sig_t;
        float inv_sr = 1.0f / sig_r;
        float mv = mask[p];

        // ---- theta weights: this lane's (up to 3) bins ----
        float wts[3];
        #pragma unroll
        for (int k = 0; k < 3; ++k) {
            int t = lane + 64 * k;
            float wv = 0.0f;
            if (t < TBINS) {
                float e0 = THETA_MIN + ((float)t - 0.5f) * T_BIN;
                float e1 = THETA_MIN + ((float)t + 0.5f) * T_BIN;
                wv = phi_cdf((e1 - pp.theta) * inv_st) - phi_cdf((e0 - pp.theta) * inv_st);
                wv *= mv;
                if (wv < 1e-9f) wv = 0.0f;   // tail truncation, error << threshold
            }
            wts[k] = wv;
        }

        // ---- rho window [jlo, jhi] (8.5 sigma + margin) ----
        float rad = 8.5f * sig_r;
        int jlo = (int)floorf((pp.rho - rad - R_MIN) / R_BIN - 0.5f);
        int jhi = (int)ceilf((pp.rho + rad - R_MIN) / R_BIN + 0.5f);
        jlo = max(jlo, 0);
        jhi = min(jhi, RBINS - 1);

        for (int jb = jlo; jb <= jhi; jb += 64) {
            int j = jb + lane;
            float wr = 0.0f;
            if (j <= jhi) {
                float e0 = R_MIN + ((float)j - 0.5f) * R_BIN;
                float e1 = R_MIN + ((float)j + 0.5f) * R_BIN;
                wr = phi_cdf((e1 - pp.rho) * inv_sr) - phi_cdf((e0 - pp.rho) * inv_sr);
            }
            int wcnt = min(64, jhi - jb + 1);
            for (int jj = 0; jj < wcnt; ++jj) {
                float wrj = __shfl(wr, jj, 64);
                if (wrj != 0.0f) {
                    int col = jb + jj;
                    if (wts[0] != 0.0f)
                        atomicAdd(&acc[lane * RBINS + col], wts[0] * wrj);
                    if (wts[1] != 0.0f)
                        atomicAdd(&acc[(lane + 64) * RBINS + col], wts[1] * wrj);
                    if (lane + 128 < TBINS && wts[2] != 0.0f)
                        atomicAdd(&acc[(lane + 128) * RBINS + col], wts[2] * wrj);
                }
            }
        }
    }
}

extern "C" void kernel_launch(void* const* d_in, const int* in_sizes, int n_in,
                              void* d_out, int out_size, void* d_ws, size_t ws_size,
                              hipStream_t stream) {
    const float* img  = (const float*)d_in[0];
    const float* mask = (const float*)d_in[1];
    float* acc = (float*)d_out;

    // ws layout: [0] int count ; [64 ints offset] int list[NPIX]  (~1.05 MB)
    int* count = (int*)d_ws;
    int* list  = (int*)d_ws + 64;

    hipLaunchKernelGGL(init_kernel, dim3((TBINS * RBINS + 255) / 256), dim3(256), 0, stream,
                       acc, count);
    hipLaunchKernelGGL(prep_kernel, dim3(NPIX / 256), dim3(256), 0, stream,
                       img, mask, count, list);
    hipLaunchKernelGGL(vote_kernel, dim3(1024), dim3(256), 0, stream,
                       img, mask, list, count, acc);
}

// Round 2
// 905.205 us; speedup vs baseline: 2.5351x; 2.5351x over previous
//
#include <hip/hip_runtime.h>
#include <math.h>

#define H 512
#define W 512
#define TBINS 180
#define RBINS 360
#define NPIX (H*W)
#define NCELL (TBINS*RBINS)

#define THETA_MIN (-1.5707963267948966f)
#define T_BIN ((float)(3.141592653589793 / 179.0))
#define R_MIN (-724.0773439350246f)
#define R_BIN ((float)(2.0 * 724.0773439350246 / 359.0))
#define THR_VAR 100.0f

#define CAP 49152          // valid-pixel list capacity (~26k expected)
#define RT 6               // rho tiles of 64 cols (6*64=384 >= 360)
#define CCHUNK 44          // chunks per rho tile -> 264 blocks
#define TCELLS (TBINS*64)  // 11520 LDS cells per tile

__device__ __forceinline__ float phi_cdf(float z) {
    return 0.5f * erfcf(-0.70710678118654752f * z);
}

struct PixParams { float theta, rho, var_theta, var_rho; };

// Faithful to reference incl. the row_s quirk (residual uses img[clip(hi+dx), wi]).
__device__ __forceinline__ PixParams compute_pixel(const float* __restrict__ img,
                                                   int hi, int wi) {
    int xm = max(hi - 1, 0), xp = min(hi + 1, H - 1);
    int ym = max(wi - 1, 0), yp = min(wi + 1, W - 1);
    const float* r0 = img + xm * W;
    const float* r1 = img + hi * W;
    const float* r2 = img + xp * W;
    float s00 = r0[ym], s01 = r0[wi], s02 = r0[yp];
    float s10 = r1[ym], s11 = r1[wi], s12 = r1[yp];
    float s20 = r2[ym], s21 = r2[wi], s22 = r2[yp];

    float alpha_s = (s20 + s21 + s22) - (s00 + s01 + s02);
    float beta_s  = (s02 + s12 + s22) - (s00 + s10 + s20);
    float gsum    = s00 + s01 + s02 + s10 + s11 + s12 + s20 + s21 + s22;

    float alpha = alpha_s * (1.0f / 6.0f) + 1e-6f;
    float beta  = beta_s  * (1.0f / 6.0f) + 1e-6f;
    float gamma = gsum * (1.0f / 9.0f);

    float cvals[3] = { s01, s11, s21 };
    float eps2 = 0.0f;
    #pragma unroll
    for (int ix = 0; ix < 3; ++ix) {
        float dx = (float)(ix - 1);
        float c = cvals[ix];
        #pragma unroll
        for (int iy = 0; iy < 3; ++iy) {
            float dy = (float)(iy - 1);
            float r = c - alpha * dy - beta * dx - gamma;
            eps2 += r * r;
        }
    }
    float noise_var = eps2 * (1.0f / 7.0f);
    float va = noise_var * (1.0f / 6.0f);
    float g2 = alpha * alpha + beta * beta;
    float var_theta = (beta * beta * va + alpha * alpha * va) / (g2 * g2);

    float theta = atanf(beta / alpha);
    float ct = cosf(theta), st = sinf(theta);
    float x = (float)hi, y = (float)wi;
    float rho = x * ct + y * st;
    float drho = -x * st + y * ct;

    PixParams pp;
    pp.theta = theta; pp.rho = rho; pp.var_theta = var_theta;
    pp.var_rho = drho * drho * var_theta;
    return pp;
}

__global__ void init_kernel(float* __restrict__ out, float* __restrict__ p1,
                            float* __restrict__ p2, int* __restrict__ count) {
    int i = blockIdx.x * blockDim.x + threadIdx.x;
    if (i < NCELL) { out[i] = 0.0f; p1[i] = 0.0f; p2[i] = 0.0f; }
    if (i == 0) *count = 0;
}

__global__ void prep_kernel(const float* __restrict__ img,
                            const float* __restrict__ mask,
                            int* __restrict__ count,
                            int2* __restrict__ list) {
    int p = blockIdx.x * blockDim.x + threadIdx.x;
    if (p >= NPIX) return;
    int hi = p >> 9, wi = p & (W - 1);
    PixParams pp = compute_pixel(img, hi, wi);
    if (!(pp.var_theta <= THR_VAR) || !(pp.var_rho <= THR_VAR) || mask[p] == 0.0f)
        return;
    float sig_r = sqrtf(pp.var_rho + 1e-12f);
    float rad = 8.5f * sig_r;
    int rlo = (int)floorf((pp.rho - rad - R_MIN) / R_BIN - 0.5f);
    int rhi = (int)ceilf((pp.rho + rad - R_MIN) / R_BIN + 0.5f);
    rlo = max(rlo, 0); rhi = min(rhi, RBINS - 1);
    if (rhi < rlo) return;  // window entirely outside accumulator range
    int pos = atomicAdd(count, 1);
    if (pos < CAP) {
        int2 e; e.x = p; e.y = rlo | (rhi << 16);
        list[pos] = e;
    }
}

// One wave per pixel, block privatizes a 180x64 rho-tile slab in LDS.
__global__ void __launch_bounds__(256)
vote_kernel(const float* __restrict__ img,
            const float* __restrict__ mask,
            const int2* __restrict__ list,
            const int* __restrict__ count,
            float* __restrict__ out, float* __restrict__ p1, float* __restrict__ p2) {
    __shared__ float tile[TCELLS];
    __shared__ float ebuf[4 * 184];

    int rt = blockIdx.x / CCHUNK;      // 0..RT-1
    int chunk = blockIdx.x % CCHUNK;   // 0..CCHUNK-1
    int c0 = rt * 64;
    int wv = threadIdx.x >> 6, lane = threadIdx.x & 63;

    for (int k = threadIdx.x; k < TCELLS; k += 256) tile[k] = 0.0f;
    __syncthreads();

    int n = min(*count, CAP);
    float* eb = ebuf + wv * 184;

    for (int i = chunk * 4 + wv; i < n; i += CCHUNK * 4) {
        int2 e = list[i];
        int rlo = e.y & 0xffff, rhi = e.y >> 16;
        if (rhi < c0 || rlo > c0 + 63) continue;   // rho window misses this tile

        int p = e.x;
        int hi = p >> 9, wi = p & (W - 1);
        PixParams pp = compute_pixel(img, hi, wi);
        float sig_t = sqrtf(pp.var_theta + 1e-12f);
        float sig_r = sqrtf(pp.var_rho + 1e-12f);
        float ist = 1.0f / sig_t, isr = 1.0f / sig_r;
        float mv = mask[p];

        // theta window (8.5 sigma; truncated mass < 1e-16)
        float radt = 8.5f * sig_t;
        int tlo = (int)floorf((pp.theta - radt - THETA_MIN) / T_BIN - 0.5f);
        int thi = (int)ceilf((pp.theta + radt - THETA_MIN) / T_BIN + 0.5f);
        tlo = max(tlo, 0); thi = min(thi, TBINS - 1);
        int ne = thi - tlo + 2;   // edge cdfs tlo .. thi+1

        #pragma unroll
        for (int k = 0; k < 3; ++k) {
            int ei = lane + 64 * k;
            if (ei < ne) {
                float edge = THETA_MIN + ((float)(tlo + ei) - 0.5f) * T_BIN;
                eb[ei] = phi_cdf((edge - pp.theta) * ist);
            }
        }

        // rho weight for this lane's column
        int col = c0 + lane;
        float wr = 0.0f;
        if (col < RBINS) {
            float e0 = R_MIN + ((float)col - 0.5f) * R_BIN;
            float e1 = e0 + R_BIN;
            wr = (phi_cdf((e1 - pp.rho) * isr) - phi_cdf((e0 - pp.rho) * isr)) * mv;
        }

        float prev = eb[0];
        for (int t = tlo; t <= thi; ++t) {
            float cur = eb[t - tlo + 1];
            float wt = cur - prev;
            prev = cur;
            if (wt != 0.0f && wr != 0.0f)
                atomicAdd(&tile[t * 64 + lane], wt * wr);
        }
    }

    __syncthreads();

    // flush LDS tile to one of 3 partial accumulators, rotated start per block
    int sel = blockIdx.x % 3;
    float* dst = (sel == 0) ? out : (sel == 1 ? p1 : p2);
    int start = (int)(((unsigned)blockIdx.x * 2654435761u) % (unsigned)TCELLS);
    for (int k = threadIdx.x; k < TCELLS; k += 256) {
        int cc = k + start; if (cc >= TCELLS) cc -= TCELLS;
        float v = tile[cc];
        if (v != 0.0f) {
            int t = cc >> 6, cl = cc & 63;
            int col = c0 + cl;
            if (col < RBINS) atomicAdd(&dst[t * RBINS + col], v);
        }
    }
}

__global__ void reduce_kernel(float* __restrict__ out, const float* __restrict__ p1,
                              const float* __restrict__ p2) {
    int i = blockIdx.x * blockDim.x + threadIdx.x;
    if (i < NCELL) out[i] = out[i] + p1[i] + p2[i];
}

extern "C" void kernel_launch(void* const* d_in, const int* in_sizes, int n_in,
                              void* d_out, int out_size, void* d_ws, size_t ws_size,
                              hipStream_t stream) {
    const float* img  = (const float*)d_in[0];
    const float* mask = (const float*)d_in[1];
    float* out = (float*)d_out;

    // ws layout (<=0.9 MB): count @0 ; list @256 (8B*CAP=384KB) ; p1 ; p2
    char* ws = (char*)d_ws;
    int*  count = (int*)ws;
    int2* list  = (int2*)(ws + 256);
    float* p1   = (float*)(ws + 256 + 8 * CAP);            // 393472
    float* p2   = (float*)(ws + 256 + 8 * CAP + 260096);   // 653568

    hipLaunchKernelGGL(init_kernel, dim3((NCELL + 255) / 256), dim3(256), 0, stream,
                       out, p1, p2, count);
    hipLaunchKernelGGL(prep_kernel, dim3(NPIX / 256), dim3(256), 0, stream,
                       img, mask, count, list);
    hipLaunchKernelGGL(vote_kernel, dim3(RT * CCHUNK), dim3(256), 0, stream,
                       img, mask, list, count, out, p1, p2);
    hipLaunchKernelGGL(reduce_kernel, dim3((NCELL + 255) / 256), dim3(256), 0, stream,
                       out, p1, p2);
}

// Round 3
// 461.989 us; speedup vs baseline: 4.9671x; 1.9594x over previous
//
#include <hip/hip_runtime.h>
#include <math.h>

#define H 512
#define W 512
#define TBINS 180
#define RBINS 360
#define NPIX (H*W)
#define NCELL (TBINS*RBINS)

#define THETA_MIN (-1.5707963267948966f)
#define T_BIN ((float)(3.141592653589793 / 179.0))
#define R_MIN (-724.0773439350246f)
#define R_BIN ((float)(2.0 * 724.0773439350246 / 359.0))
#define THR_VAR 100.0f

#define CAP 49152
#define RT 6              // rho tiles of 64 cols
#define CH 96             // chunks per tile -> 576 vote blocks
#define VBLK 512          // vote block: 8 waves
#define TCELLS (TBINS*64) // 11520 LDS cells

__device__ __forceinline__ float phi_cdf(float z) {
    return 0.5f * erfcf(-0.70710678118654752f * z);
}

struct PixParams { float theta, rho, var_theta, var_rho; };

// Faithful to reference incl. row_s quirk (residual uses img[clip(hi+dx), wi]).
__device__ __forceinline__ PixParams compute_pixel(const float* __restrict__ img,
                                                   int hi, int wi) {
    int xm = max(hi - 1, 0), xp = min(hi + 1, H - 1);
    int ym = max(wi - 1, 0), yp = min(wi + 1, W - 1);
    const float* r0 = img + xm * W;
    const float* r1 = img + hi * W;
    const float* r2 = img + xp * W;
    float s00 = r0[ym], s01 = r0[wi], s02 = r0[yp];
    float s10 = r1[ym], s11 = r1[wi], s12 = r1[yp];
    float s20 = r2[ym], s21 = r2[wi], s22 = r2[yp];

    float alpha_s = (s20 + s21 + s22) - (s00 + s01 + s02);
    float beta_s  = (s02 + s12 + s22) - (s00 + s10 + s20);
    float gsum    = s00 + s01 + s02 + s10 + s11 + s12 + s20 + s21 + s22;

    float alpha = alpha_s * (1.0f / 6.0f) + 1e-6f;
    float beta  = beta_s  * (1.0f / 6.0f) + 1e-6f;
    float gamma = gsum * (1.0f / 9.0f);

    float cvals[3] = { s01, s11, s21 };
    float eps2 = 0.0f;
    #pragma unroll
    for (int ix = 0; ix < 3; ++ix) {
        float dx = (float)(ix - 1);
        float c = cvals[ix];
        #pragma unroll
        for (int iy = 0; iy < 3; ++iy) {
            float dy = (float)(iy - 1);
            float r = c - alpha * dy - beta * dx - gamma;
            eps2 += r * r;
        }
    }
    float noise_var = eps2 * (1.0f / 7.0f);
    float va = noise_var * (1.0f / 6.0f);
    float g2 = alpha * alpha + beta * beta;
    float var_theta = (beta * beta * va + alpha * alpha * va) / (g2 * g2);

    float theta = atanf(beta / alpha);
    float ct = cosf(theta), st = sinf(theta);
    float x = (float)hi, y = (float)wi;
    float rho = x * ct + y * st;
    float drho = -x * st + y * ct;

    PixParams pp;
    pp.theta = theta; pp.rho = rho; pp.var_theta = var_theta;
    pp.var_rho = drho * drho * var_theta;
    return pp;
}

__global__ void init_kernel(float* __restrict__ out, float* __restrict__ p1,
                            float* __restrict__ p2, float* __restrict__ p3,
                            int* __restrict__ count) {
    int i = blockIdx.x * blockDim.x + threadIdx.x;
    if (i < NCELL) { out[i] = 0.0f; p1[i] = 0.0f; p2[i] = 0.0f; p3[i] = 0.0f; }
    if (i == 0) *count = 0;
}

__global__ void prep_kernel(const float* __restrict__ img,
                            const float* __restrict__ mask,
                            int* __restrict__ count,
                            float4* __restrict__ recs,
                            int4* __restrict__ aux) {
    int p = blockIdx.x * blockDim.x + threadIdx.x;
    if (p >= NPIX) return;
    int hi = p >> 9, wi = p & (W - 1);
    float mv = mask[p];
    PixParams pp = compute_pixel(img, hi, wi);
    if (!(pp.var_theta <= THR_VAR) || !(pp.var_rho <= THR_VAR) || mv == 0.0f)
        return;
    float sig_t = sqrtf(pp.var_theta + 1e-12f);
    float sig_r = sqrtf(pp.var_rho + 1e-12f);

    float radr = 8.5f * sig_r;
    int rlo = (int)floorf((pp.rho - radr - R_MIN) / R_BIN - 0.5f);
    int rhi = (int)ceilf((pp.rho + radr - R_MIN) / R_BIN + 0.5f);
    rlo = max(rlo, 0); rhi = min(rhi, RBINS - 1);
    if (rhi < rlo) return;  // rho window misses accumulator entirely

    float radt = 8.5f * sig_t;
    int tlo = (int)floorf((pp.theta - radt - THETA_MIN) / T_BIN - 0.5f);
    int thi = (int)ceilf((pp.theta + radt - THETA_MIN) / T_BIN + 0.5f);
    tlo = max(tlo, 0); thi = min(thi, TBINS - 1);

    int pos = atomicAdd(count, 1);
    if (pos < CAP) {
        float4 rc; rc.x = pp.theta; rc.y = 1.0f / sig_t; rc.z = pp.rho; rc.w = 1.0f / sig_r;
        recs[pos] = rc;
        int4 ax; ax.x = rlo | (rhi << 16); ax.y = tlo | (thi << 16);
        ax.z = __float_as_int(mv); ax.w = 0;
        aux[pos] = ax;
    }
}

// 512 threads / 8 waves per block; block privatizes a 180x64 rho-tile in LDS.
// All per-pixel params precomputed -> hot loop is loads + erfcf + ds_add.
__global__ void __launch_bounds__(VBLK)
vote_kernel(const float4* __restrict__ recs,
            const int4* __restrict__ aux,
            const int* __restrict__ count,
            float* __restrict__ out, float* __restrict__ p1,
            float* __restrict__ p2, float* __restrict__ p3) {
    __shared__ float tile[TCELLS];
    __shared__ float ebuf[8 * 184];

    int rt = blockIdx.x % RT;          // interleave tiles across adjacent blocks
    int chunk = blockIdx.x / RT;       // 0..CH-1
    int c0 = rt * 64;
    int wv = threadIdx.x >> 6, lane = threadIdx.x & 63;

    for (int k = threadIdx.x; k < TCELLS; k += VBLK) tile[k] = 0.0f;
    __syncthreads();

    int n = min(*count, CAP);
    float* eb = ebuf + wv * 184;

    for (int i = chunk * 8 + wv; i < n; i += CH * 8) {
        int4 ax = aux[i];
        int rlo = ax.x & 0xffff, rhi = ax.x >> 16;
        if (rhi < c0 || rlo > c0 + 63) continue;

        float4 rc = recs[i];
        float theta = rc.x, ist = rc.y, rho = rc.z, isr = rc.w;
        float mv = __int_as_float(ax.z);
        int tlo = ax.y & 0xffff, thi = ax.y >> 16;
        int ne = thi - tlo + 2;        // edge CDFs tlo..thi+1

        #pragma unroll
        for (int k = 0; k < 3; ++k) {
            int ei = lane + 64 * k;
            if (ei < ne) {
                float edge = THETA_MIN + ((float)(tlo + ei) - 0.5f) * T_BIN;
                eb[ei] = phi_cdf((edge - theta) * ist);
            }
        }

        int col = c0 + lane;
        float wr = 0.0f;
        if (col < RBINS) {
            float e0 = R_MIN + ((float)col - 0.5f) * R_BIN;
            float e1 = e0 + R_BIN;
            wr = (phi_cdf((e1 - rho) * isr) - phi_cdf((e0 - rho) * isr)) * mv;
        }

        float prev = eb[0];
        for (int t = tlo; t <= thi; ++t) {
            float cur = eb[t - tlo + 1];
            float w = (cur - prev) * wr;
            prev = cur;
            if (w != 0.0f)
                atomicAdd(&tile[t * 64 + lane], w);
        }
    }

    __syncthreads();

    // flush to 1 of 4 accumulators, hashed start to decorrelate lines
    int sel = blockIdx.x & 3;
    float* dst = (sel == 0) ? out : (sel == 1 ? p1 : (sel == 2 ? p2 : p3));
    int start = (int)(((unsigned)blockIdx.x * 2654435761u) % (unsigned)TCELLS);
    for (int k = threadIdx.x; k < TCELLS; k += VBLK) {
        int cc = k + start; if (cc >= TCELLS) cc -= TCELLS;
        float v = tile[cc];
        if (v != 0.0f) {
            int t = cc >> 6, cl = cc & 63;
            int col = c0 + cl;
            if (col < RBINS) atomicAdd(&dst[t * RBINS + col], v);
        }
    }
}

__global__ void reduce_kernel(float* __restrict__ out, const float* __restrict__ p1,
                              const float* __restrict__ p2, const float* __restrict__ p3) {
    int i = blockIdx.x * blockDim.x + threadIdx.x;
    if (i < NCELL) out[i] = out[i] + p1[i] + p2[i] + p3[i];
}

extern "C" void kernel_launch(void* const* d_in, const int* in_sizes, int n_in,
                              void* d_out, int out_size, void* d_ws, size_t ws_size,
                              hipStream_t stream) {
    const float* img  = (const float*)d_in[0];
    const float* mask = (const float*)d_in[1];
    float* out = (float*)d_out;

    // ws layout (~2.25 MB): count@0 ; recs@256 (786432) ; aux (786432) ;
    // p1,p2,p3 (259328 each, 256-aligned)
    char* ws = (char*)d_ws;
    int*    count = (int*)ws;
    float4* recs  = (float4*)(ws + 256);
    int4*   aux   = (int4*)(ws + 256 + 786432);
    float*  p1    = (float*)(ws + 1573120);
    float*  p2    = (float*)(ws + 1573120 + 259328);
    float*  p3    = (float*)(ws + 1573120 + 2 * 259328);

    hipLaunchKernelGGL(init_kernel, dim3((NCELL + 255) / 256), dim3(256), 0, stream,
                       out, p1, p2, p3, count);
    hipLaunchKernelGGL(prep_kernel, dim3(NPIX / 256), dim3(256), 0, stream,
                       img, mask, count, recs, aux);
    hipLaunchKernelGGL(vote_kernel, dim3(RT * CH), dim3(VBLK), 0, stream,
                       recs, aux, count, out, p1, p2, p3);
    hipLaunchKernelGGL(reduce_kernel, dim3((NCELL + 255) / 256), dim3(256), 0, stream,
                       out, p1, p2, p3);
}